// Round 1
// baseline (770.956 us; speedup 1.0000x reference)
//
#include <hip/hip_runtime.h>
#include <math.h>

#define NN 100000
#define NE 1600000
#define F_IN 128
#define F_OUT 40

// ---- degree count: deg[col[e]] += 1 ----
__global__ void deg_kernel(const int* __restrict__ col, float* __restrict__ deg, int E) {
    int i = blockIdx.x * blockDim.x + threadIdx.x;
    if (i < E) atomicAdd(&deg[col[i]], 1.0f);
}

// ---- dinv = rsqrt(deg + 1)  (self loop adds 1; deg+1 > 0 always) ----
__global__ void dinv_kernel(float* __restrict__ deg, int N) {
    int i = blockIdx.x * blockDim.x + threadIdx.x;
    if (i < N) deg[i] = rsqrtf(deg[i] + 1.0f);
}

// ---- xw = x @ W   ([N,128] @ [128,40]) ; one 64-lane wave per node ----
__global__ void gemm_kernel(const float* __restrict__ x, const float* __restrict__ w,
                            float* __restrict__ xw, int N) {
    __shared__ float sh_w[F_IN * F_OUT];   // 20 KB
    __shared__ float sh_x[4][F_IN];        // 2 KB (4 waves/block)
    // stage W
    for (int i = threadIdx.x; i < F_IN * F_OUT; i += blockDim.x)
        sh_w[i] = w[i];
    int wave = threadIdx.x >> 6;
    int lane = threadIdx.x & 63;
    int n = blockIdx.x * 4 + wave;
    if (n < N) {
        // stage this node's x row: 64 lanes x 2 floats
        sh_x[wave][lane]      = x[n * F_IN + lane];
        sh_x[wave][lane + 64] = x[n * F_IN + lane + 64];
    }
    __syncthreads();
    if (n >= N || lane >= F_OUT) return;
    float acc = 0.f;
#pragma unroll
    for (int k = 0; k < F_IN; ++k)
        acc = fmaf(sh_x[wave][k], sh_w[k * F_OUT + lane], acc);
    xw[n * F_OUT + lane] = acc;
}

// ---- y[i][j] = src[i][j] * dinv[i]^2   (self-loop term, also zero-init) ----
__global__ void init_y(const float* __restrict__ src, const float* __restrict__ dinv,
                       float* __restrict__ y, int total) {
    int i = blockIdx.x * blockDim.x + threadIdx.x;
    if (i < total) {
        int n = i / F_OUT;
        float d = dinv[n];
        y[i] = src[i] * d * d;
    }
}

// ---- edge scatter: y[c] += src[r] * dinv[r]*dinv[c] ; one wave per edge ----
__global__ void scatter_kernel(const int* __restrict__ row, const int* __restrict__ col,
                               const float* __restrict__ dinv,
                               const float* __restrict__ src, float* __restrict__ dst,
                               int E) {
    int gtid = blockIdx.x * blockDim.x + threadIdx.x;
    int e = gtid >> 6;
    int lane = gtid & 63;
    if (e >= E) return;
    int r = row[e];
    int c = col[e];
    float coef = dinv[r] * dinv[c];
    if (lane < F_OUT)
        atomicAdd(&dst[c * F_OUT + lane], src[r * F_OUT + lane] * coef);
}

// ---- out = log_softmax(y + bias) ; one wave per node ----
__global__ void out_kernel(const float* __restrict__ y, const float* __restrict__ bias,
                           float* __restrict__ out, int N) {
    int n = blockIdx.x * 4 + (threadIdx.x >> 6);
    int lane = threadIdx.x & 63;
    if (n >= N) return;
    float logit = 0.f;
    float v = -INFINITY;
    if (lane < F_OUT) {
        logit = y[n * F_OUT + lane] + bias[lane];
        v = logit;
    }
#pragma unroll
    for (int off = 32; off; off >>= 1) v = fmaxf(v, __shfl_xor(v, off));
    float e = (lane < F_OUT) ? expf(logit - v) : 0.f;
#pragma unroll
    for (int off = 32; off; off >>= 1) e += __shfl_xor(e, off);
    if (lane < F_OUT) out[n * F_OUT + lane] = logit - v - logf(e);
}

extern "C" void kernel_launch(void* const* d_in, const int* in_sizes, int n_in,
                              void* d_out, int out_size, void* d_ws, size_t ws_size,
                              hipStream_t stream) {
    const float* x    = (const float*)d_in[0];
    const int*   eidx = (const int*)d_in[1];   // [2, E] int32 (JAX x64 disabled)
    const float* w    = (const float*)d_in[2];
    const float* bias = (const float*)d_in[3];
    float* out = (float*)d_out;

    const int E = in_sizes[1] / 2;   // 1,600,000
    const int N = NN;

    float* wsf  = (float*)d_ws;
    float* dinv = wsf;                       // N floats (deg, then dinv in place)
    float* xw   = wsf + N;                   // N*F_OUT
    float* y1   = xw + (size_t)N * F_OUT;    // N*F_OUT
    float* y2   = y1 + (size_t)N * F_OUT;    // N*F_OUT

    const int* row = eidx;
    const int* col = eidx + E;

    hipMemsetAsync(dinv, 0, (size_t)N * sizeof(float), stream);
    deg_kernel<<<(E + 255) / 256, 256, 0, stream>>>(col, dinv, E);
    dinv_kernel<<<(N + 255) / 256, 256, 0, stream>>>(dinv, N);

    gemm_kernel<<<(N + 3) / 4, 256, 0, stream>>>(x, w, xw, N);

    const int total = N * F_OUT;
    long long sthreads = (long long)E * 64;
    int sblocks = (int)((sthreads + 255) / 256);

    // hop 1
    init_y<<<(total + 255) / 256, 256, 0, stream>>>(xw, dinv, y1, total);
    scatter_kernel<<<sblocks, 256, 0, stream>>>(row, col, dinv, xw, y1, E);
    // hop 2
    init_y<<<(total + 255) / 256, 256, 0, stream>>>(y1, dinv, y2, total);
    scatter_kernel<<<sblocks, 256, 0, stream>>>(row, col, dinv, y1, y2, E);

    out_kernel<<<(N + 3) / 4, 256, 0, stream>>>(y2, bias, out, N);
}

// Round 2
// 441.621 us; speedup vs baseline: 1.7457x; 1.7457x over previous
//
#include <hip/hip_runtime.h>
#include <math.h>

#define NN 100000
#define F_IN 128
#define F_OUT 40
#define F_PAD 48   // padded row stride: 192 B, 64 B aligned -> exactly 2 cache lines per gather

// ---- deg[col[e]] += 1 (int) ----
__global__ void deg_kernel(const int* __restrict__ col, int* __restrict__ deg, int E) {
    int i = blockIdx.x * blockDim.x + threadIdx.x;
    if (i < E) atomicAdd(&deg[col[i]], 1);
}

// ---- block-level exclusive scan (256/block), emits per-block sums ----
__global__ void scan1_kernel(const int* __restrict__ deg, int* __restrict__ offs,
                             int* __restrict__ partial, int N) {
    __shared__ int sh[256];
    int gid = blockIdx.x * 256 + threadIdx.x;
    int v = (gid < N) ? deg[gid] : 0;
    sh[threadIdx.x] = v;
    __syncthreads();
    for (int off = 1; off < 256; off <<= 1) {
        int t = (threadIdx.x >= off) ? sh[threadIdx.x - off] : 0;
        __syncthreads();
        sh[threadIdx.x] += t;
        __syncthreads();
    }
    if (gid < N) offs[gid] = sh[threadIdx.x] - v;   // exclusive
    if (threadIdx.x == 255) partial[blockIdx.x] = sh[255];
}

// ---- scan the per-block sums (single block, nb <= 512) ----
__global__ void scan2_kernel(int* __restrict__ partial, int nb) {
    __shared__ int sh[512];
    int v = (threadIdx.x < nb) ? partial[threadIdx.x] : 0;
    sh[threadIdx.x] = v;
    __syncthreads();
    for (int off = 1; off < 512; off <<= 1) {
        int t = (threadIdx.x >= off) ? sh[threadIdx.x - off] : 0;
        __syncthreads();
        sh[threadIdx.x] += t;
        __syncthreads();
    }
    if (threadIdx.x < nb) partial[threadIdx.x] = sh[threadIdx.x] - v;  // exclusive
}

// ---- add block offsets; also init cursor = offs ----
__global__ void scan3_kernel(int* __restrict__ offs, const int* __restrict__ partial,
                             int* __restrict__ cursor, int N) {
    int gid = blockIdx.x * 256 + threadIdx.x;
    if (gid < N) {
        int o = offs[gid] + partial[blockIdx.x];
        offs[gid] = o;
        cursor[gid] = o;
    }
}

// ---- dinv = rsqrt(deg + 1) ----
__global__ void dinv_kernel(const int* __restrict__ deg, float* __restrict__ dinv, int N) {
    int i = blockIdx.x * blockDim.x + threadIdx.x;
    if (i < N) dinv[i] = rsqrtf((float)deg[i] + 1.0f);
}

// ---- CSR fill: adj[cursor[c]++] = row[e] ----
__global__ void fill_kernel(const int* __restrict__ row, const int* __restrict__ col,
                            int* __restrict__ cursor, int* __restrict__ adj, int E) {
    int e = blockIdx.x * blockDim.x + threadIdx.x;
    if (e < E) {
        int c = col[e];
        int pos = atomicAdd(&cursor[c], 1);
        adj[pos] = row[e];
    }
}

// ---- xs1 = (x @ W) * dinv[n] ; one wave per node ----
__global__ void gemm_kernel(const float* __restrict__ x, const float* __restrict__ w,
                            const float* __restrict__ dinv, float* __restrict__ xs1, int N) {
    __shared__ float sh_w[F_IN * F_OUT];   // 20 KB
    __shared__ float sh_x[4][F_IN];        // 2 KB
    for (int i = threadIdx.x; i < F_IN * F_OUT; i += blockDim.x)
        sh_w[i] = w[i];
    int wave = threadIdx.x >> 6;
    int lane = threadIdx.x & 63;
    int n = blockIdx.x * 4 + wave;
    if (n < N) {
        sh_x[wave][lane]      = x[n * F_IN + lane];
        sh_x[wave][lane + 64] = x[n * F_IN + lane + 64];
    }
    __syncthreads();
    if (n >= N || lane >= F_OUT) return;
    float acc = 0.f;
#pragma unroll
    for (int k = 0; k < F_IN; ++k)
        acc = fmaf(sh_x[wave][k], sh_w[k * F_OUT + lane], acc);
    xs1[(size_t)n * F_PAD + lane] = acc * dinv[n];
}

// ---- hop 1 gather: xs2[c] = dinv[c]^2 * (xs1[c] + sum_{r in in(c)} xs1[r]) ----
__global__ void hop1_kernel(const int* __restrict__ offs, const int* __restrict__ ends,
                            const int* __restrict__ adj, const float* __restrict__ dinv,
                            const float* __restrict__ xs, float* __restrict__ xs_next, int N) {
    int n = blockIdx.x * 4 + (threadIdx.x >> 6);
    int lane = threadIdx.x & 63;
    if (n >= N || lane >= F_OUT) return;
    int b = offs[n], e = ends[n];
    float a0 = xs[(size_t)n * F_PAD + lane], a1 = 0.f, a2 = 0.f, a3 = 0.f;
    int k = b;
    for (; k + 3 < e; k += 4) {
        int r0 = adj[k], r1 = adj[k + 1], r2 = adj[k + 2], r3 = adj[k + 3];
        a0 += xs[(size_t)r0 * F_PAD + lane];
        a1 += xs[(size_t)r1 * F_PAD + lane];
        a2 += xs[(size_t)r2 * F_PAD + lane];
        a3 += xs[(size_t)r3 * F_PAD + lane];
    }
    for (; k < e; ++k) a0 += xs[(size_t)adj[k] * F_PAD + lane];
    float d = dinv[n];
    xs_next[(size_t)n * F_PAD + lane] = (a0 + a1 + a2 + a3) * d * d;
}

// ---- hop 2 gather + bias + log_softmax -> out ----
__global__ void hop2_kernel(const int* __restrict__ offs, const int* __restrict__ ends,
                            const int* __restrict__ adj, const float* __restrict__ dinv,
                            const float* __restrict__ xs, const float* __restrict__ bias,
                            float* __restrict__ out, int N) {
    int n = blockIdx.x * 4 + (threadIdx.x >> 6);
    int lane = threadIdx.x & 63;
    if (n >= N) return;
    int b = offs[n], e = ends[n];
    if (lane >= F_OUT) e = b;   // idle lanes: empty loop, but stay for shuffles
    float a0 = (lane < F_OUT) ? xs[(size_t)n * F_PAD + lane] : 0.f;
    float a1 = 0.f, a2 = 0.f, a3 = 0.f;
    int k = b;
    for (; k + 3 < e; k += 4) {
        int r0 = adj[k], r1 = adj[k + 1], r2 = adj[k + 2], r3 = adj[k + 3];
        a0 += xs[(size_t)r0 * F_PAD + lane];
        a1 += xs[(size_t)r1 * F_PAD + lane];
        a2 += xs[(size_t)r2 * F_PAD + lane];
        a3 += xs[(size_t)r3 * F_PAD + lane];
    }
    for (; k < e; ++k) a0 += xs[(size_t)adj[k] * F_PAD + lane];

    float logit = 0.f, v = -INFINITY;
    if (lane < F_OUT) {
        logit = (a0 + a1 + a2 + a3) * dinv[n] + bias[lane];
        v = logit;
    }
#pragma unroll
    for (int off = 32; off; off >>= 1) v = fmaxf(v, __shfl_xor(v, off));
    float ex = (lane < F_OUT) ? expf(logit - v) : 0.f;
#pragma unroll
    for (int off = 32; off; off >>= 1) ex += __shfl_xor(ex, off);
    if (lane < F_OUT) out[(size_t)n * F_OUT + lane] = logit - v - logf(ex);
}

extern "C" void kernel_launch(void* const* d_in, const int* in_sizes, int n_in,
                              void* d_out, int out_size, void* d_ws, size_t ws_size,
                              hipStream_t stream) {
    const float* x    = (const float*)d_in[0];
    const int*   eidx = (const int*)d_in[1];
    const float* w    = (const float*)d_in[2];
    const float* bias = (const float*)d_in[3];
    float* out = (float*)d_out;

    const int E = in_sizes[1] / 2;
    const int N = NN;
    const int NB = (N + 255) / 256;          // 391 scan blocks (<=512)

    char* ws = (char*)d_ws;
    int*   deg     = (int*)ws;                    ws += (size_t)N * 4;
    int*   offs    = (int*)ws;                    ws += (size_t)N * 4;
    int*   cursor  = (int*)ws;                    ws += (size_t)N * 4;
    int*   partial = (int*)ws;                    ws += 2048;
    float* dinv    = (float*)ws;                  ws += (size_t)N * 4;
    int*   adj     = (int*)ws;                    ws += (size_t)E * 4;
    float* xs1     = (float*)ws;                  ws += (size_t)N * F_PAD * 4;
    float* xs2     = (float*)ws;

    const int* row = eidx;
    const int* col = eidx + E;

    hipMemsetAsync(deg, 0, (size_t)N * sizeof(int), stream);
    deg_kernel<<<(E + 255) / 256, 256, 0, stream>>>(col, deg, E);
    scan1_kernel<<<NB, 256, 0, stream>>>(deg, offs, partial, N);
    scan2_kernel<<<1, 512, 0, stream>>>(partial, NB);
    scan3_kernel<<<NB, 256, 0, stream>>>(offs, partial, cursor, N);
    dinv_kernel<<<(N + 255) / 256, 256, 0, stream>>>(deg, dinv, N);
    fill_kernel<<<(E + 255) / 256, 256, 0, stream>>>(row, col, cursor, adj, E);

    gemm_kernel<<<(N + 3) / 4, 256, 0, stream>>>(x, w, dinv, xs1, N);

    // after fill, cursor[c] == end offset of node c
    hop1_kernel<<<(N + 3) / 4, 256, 0, stream>>>(offs, cursor, adj, dinv, xs1, xs2, N);
    hop2_kernel<<<(N + 3) / 4, 256, 0, stream>>>(offs, cursor, adj, dinv, xs2, bias, out, N);
}

// Round 3
// 292.911 us; speedup vs baseline: 2.6320x; 1.5077x over previous
//
#include <hip/hip_runtime.h>
#include <math.h>

#define NN 100000
#define F_IN 128
#define F_OUT 40
#define F_PAD 48        // padded f32 row stride: 192 B
#define BSHIFT 9        // 512 nodes per bucket
#define BSIZE (1 << BSHIFT)
#define NBUCK ((NN + BSIZE - 1) >> BSHIFT)   // 196
#define EPB_A 4096
#define EPB_C 16384

// ---- phase A: bucket histogram ----
__global__ void bhist_kernel(const int* __restrict__ col, int* __restrict__ bcount, int E) {
    __shared__ int h[NBUCK];
    for (int i = threadIdx.x; i < NBUCK; i += blockDim.x) h[i] = 0;
    __syncthreads();
    int e0 = blockIdx.x * EPB_A;
    int e1 = min(e0 + EPB_A, E);
    for (int e = e0 + threadIdx.x; e < e1; e += blockDim.x)
        atomicAdd(&h[col[e] >> BSHIFT], 1);
    __syncthreads();
    for (int i = threadIdx.x; i < NBUCK; i += blockDim.x)
        if (h[i]) atomicAdd(&bcount[i], h[i]);
}

// ---- phase B: scan bucket counts -> bbase; init bcursor ----
__global__ void bscan_kernel(const int* __restrict__ bcount, int* __restrict__ bbase,
                             int* __restrict__ bcursor) {
    __shared__ int sh[256];
    int i = threadIdx.x;
    int v = (i < NBUCK) ? bcount[i] : 0;
    sh[i] = v;
    __syncthreads();
    for (int off = 1; off < 256; off <<= 1) {
        int t = (i >= off) ? sh[i - off] : 0;
        __syncthreads();
        sh[i] += t;
        __syncthreads();
    }
    if (i < NBUCK) { int b = sh[i] - v; bbase[i] = b; bcursor[i] = b; }
}

// ---- phase C: partition edges into bucket-contiguous staging ----
__global__ void part_kernel(const int* __restrict__ row, const int* __restrict__ col,
                            int* __restrict__ bcursor, int2* __restrict__ staged, int E) {
    __shared__ int h[NBUCK];
    __shared__ int cur[NBUCK];
    for (int i = threadIdx.x; i < NBUCK; i += blockDim.x) h[i] = 0;
    __syncthreads();
    int e0 = blockIdx.x * EPB_C;
    int e1 = min(e0 + EPB_C, E);
    for (int e = e0 + threadIdx.x; e < e1; e += blockDim.x)
        atomicAdd(&h[col[e] >> BSHIFT], 1);
    __syncthreads();
    for (int i = threadIdx.x; i < NBUCK; i += blockDim.x)
        cur[i] = h[i] ? atomicAdd(&bcursor[i], h[i]) : 0;
    __syncthreads();
    for (int e = e0 + threadIdx.x; e < e1; e += blockDim.x) {
        int c = col[e];
        int pos = atomicAdd(&cur[c >> BSHIFT], 1);
        staged[pos] = make_int2(row[e], c);
    }
}

// ---- phase D: per-bucket fine CSR build + deg/offs/ends/dinv ----
__global__ void build_kernel(const int2* __restrict__ staged, const int* __restrict__ bbase,
                             int* __restrict__ adj, int* __restrict__ offs,
                             int* __restrict__ ends, float* __restrict__ dinv, int N, int E) {
    __shared__ int hist[BSIZE];
    __shared__ int cur[BSIZE];
    int bk = blockIdx.x;
    int node0 = bk << BSHIFT;
    int nn = min(BSIZE, N - node0);
    int ebase = bbase[bk];
    int eend = (bk + 1 < NBUCK) ? bbase[bk + 1] : E;
    for (int i = threadIdx.x; i < BSIZE; i += blockDim.x) hist[i] = 0;
    __syncthreads();
    for (int e = ebase + threadIdx.x; e < eend; e += blockDim.x)
        atomicAdd(&hist[staged[e].y - node0], 1);
    __syncthreads();
    int i = threadIdx.x;
    int v = (i < BSIZE) ? hist[i] : 0;
    for (int off = 1; off < BSIZE; off <<= 1) {
        int t = (i < BSIZE && i >= off) ? hist[i - off] : 0;
        __syncthreads();
        if (i < BSIZE) hist[i] += t;
        __syncthreads();
    }
    if (i < BSIZE) {
        int excl = hist[i] - v;     // exclusive intra-bucket offset
        cur[i] = excl;
        if (i < nn) {
            offs[node0 + i] = ebase + excl;
            ends[node0 + i] = ebase + excl + v;
            dinv[node0 + i] = rsqrtf((float)v + 1.0f);
        }
    }
    __syncthreads();
    for (int e = ebase + threadIdx.x; e < eend; e += blockDim.x) {
        int2 rc = staged[e];
        int pos = atomicAdd(&cur[rc.y - node0], 1);
        adj[ebase + pos] = rc.x;    // write window = this bucket's ~32 KB slice
    }
}

// ---- xs1 = (x @ W) * dinv[n] ; one wave per node ----
__global__ void gemm_kernel(const float* __restrict__ x, const float* __restrict__ w,
                            const float* __restrict__ dinv, float* __restrict__ xs1, int N) {
    __shared__ float sh_w[F_IN * F_OUT];
    __shared__ float sh_x[4][F_IN];
    for (int i = threadIdx.x; i < F_IN * F_OUT; i += blockDim.x)
        sh_w[i] = w[i];
    int wave = threadIdx.x >> 6;
    int lane = threadIdx.x & 63;
    int n = blockIdx.x * 4 + wave;
    if (n < N) {
        sh_x[wave][lane]      = x[n * F_IN + lane];
        sh_x[wave][lane + 64] = x[n * F_IN + lane + 64];
    }
    __syncthreads();
    if (n >= N || lane >= F_OUT) return;
    float acc = 0.f;
#pragma unroll
    for (int k = 0; k < F_IN; ++k)
        acc = fmaf(sh_x[wave][k], sh_w[k * F_OUT + lane], acc);
    xs1[(size_t)n * F_PAD + lane] = acc * dinv[n];
}

// ---- hop 1 gather ----
__global__ void hop1_kernel(const int* __restrict__ offs, const int* __restrict__ ends,
                            const int* __restrict__ adj, const float* __restrict__ dinv,
                            const float* __restrict__ xs, float* __restrict__ xs_next, int N) {
    int n = blockIdx.x * 4 + (threadIdx.x >> 6);
    int lane = threadIdx.x & 63;
    if (n >= N || lane >= F_OUT) return;
    int b = offs[n], e = ends[n];
    float a0 = xs[(size_t)n * F_PAD + lane], a1 = 0.f, a2 = 0.f, a3 = 0.f;
    int k = b;
    for (; k + 3 < e; k += 4) {
        int r0 = adj[k], r1 = adj[k + 1], r2 = adj[k + 2], r3 = adj[k + 3];
        a0 += xs[(size_t)r0 * F_PAD + lane];
        a1 += xs[(size_t)r1 * F_PAD + lane];
        a2 += xs[(size_t)r2 * F_PAD + lane];
        a3 += xs[(size_t)r3 * F_PAD + lane];
    }
    for (; k < e; ++k) a0 += xs[(size_t)adj[k] * F_PAD + lane];
    float d = dinv[n];
    xs_next[(size_t)n * F_PAD + lane] = (a0 + a1 + a2 + a3) * d * d;
}

// ---- hop 2 gather + bias + log_softmax ----
__global__ void hop2_kernel(const int* __restrict__ offs, const int* __restrict__ ends,
                            const int* __restrict__ adj, const float* __restrict__ dinv,
                            const float* __restrict__ xs, const float* __restrict__ bias,
                            float* __restrict__ out, int N) {
    int n = blockIdx.x * 4 + (threadIdx.x >> 6);
    int lane = threadIdx.x & 63;
    if (n >= N) return;
    int b = offs[n], e = ends[n];
    if (lane >= F_OUT) e = b;
    float a0 = (lane < F_OUT) ? xs[(size_t)n * F_PAD + lane] : 0.f;
    float a1 = 0.f, a2 = 0.f, a3 = 0.f;
    int k = b;
    for (; k + 3 < e; k += 4) {
        int r0 = adj[k], r1 = adj[k + 1], r2 = adj[k + 2], r3 = adj[k + 3];
        a0 += xs[(size_t)r0 * F_PAD + lane];
        a1 += xs[(size_t)r1 * F_PAD + lane];
        a2 += xs[(size_t)r2 * F_PAD + lane];
        a3 += xs[(size_t)r3 * F_PAD + lane];
    }
    for (; k < e; ++k) a0 += xs[(size_t)adj[k] * F_PAD + lane];

    float logit = 0.f, v = -INFINITY;
    if (lane < F_OUT) {
        logit = (a0 + a1 + a2 + a3) * dinv[n] + bias[lane];
        v = logit;
    }
#pragma unroll
    for (int off = 32; off; off >>= 1) v = fmaxf(v, __shfl_xor(v, off));
    float ex = (lane < F_OUT) ? expf(logit - v) : 0.f;
#pragma unroll
    for (int off = 32; off; off >>= 1) ex += __shfl_xor(ex, off);
    if (lane < F_OUT) out[(size_t)n * F_OUT + lane] = logit - v - logf(ex);
}

extern "C" void kernel_launch(void* const* d_in, const int* in_sizes, int n_in,
                              void* d_out, int out_size, void* d_ws, size_t ws_size,
                              hipStream_t stream) {
    const float* x    = (const float*)d_in[0];
    const int*   eidx = (const int*)d_in[1];
    const float* w    = (const float*)d_in[2];
    const float* bias = (const float*)d_in[3];
    float* out = (float*)d_out;

    const int E = in_sizes[1] / 2;
    const int N = NN;

    char* ws = (char*)d_ws;
    int*   bcount  = (int*)ws;   ws += 256 * 4;
    int*   bbase   = (int*)ws;   ws += 256 * 4;
    int*   bcursor = (int*)ws;   ws += 256 * 4;
    int*   offs    = (int*)ws;   ws += (size_t)N * 4;
    int*   ends    = (int*)ws;   ws += (size_t)N * 4;
    float* dinv    = (float*)ws; ws += (size_t)N * 4;
    int*   adj     = (int*)ws;   ws += (size_t)E * 4;
    float* xs1     = (float*)ws; ws += (size_t)N * F_PAD * 4;
    float* xs2     = (float*)ws;                       // 19.2 MB
    int2*  staged  = (int2*)xs2;                       // aliases xs2 (dead until hop1)

    const int* row = eidx;
    const int* col = eidx + E;

    hipMemsetAsync(bcount, 0, NBUCK * sizeof(int), stream);
    bhist_kernel<<<(E + EPB_A - 1) / EPB_A, 1024, 0, stream>>>(col, bcount, E);
    bscan_kernel<<<1, 256, 0, stream>>>(bcount, bbase, bcursor);
    part_kernel<<<(E + EPB_C - 1) / EPB_C, 1024, 0, stream>>>(row, col, bcursor, staged, E);
    build_kernel<<<NBUCK, 1024, 0, stream>>>(staged, bbase, adj, offs, ends, dinv, N, E);

    gemm_kernel<<<(N + 3) / 4, 256, 0, stream>>>(x, w, dinv, xs1, N);
    hop1_kernel<<<(N + 3) / 4, 256, 0, stream>>>(offs, ends, adj, dinv, xs1, xs2, N);
    hop2_kernel<<<(N + 3) / 4, 256, 0, stream>>>(offs, ends, adj, dinv, xs2, bias, out, N);
}

// Round 4
// 220.943 us; speedup vs baseline: 3.4894x; 1.3257x over previous
//
#include <hip/hip_runtime.h>
#include <math.h>

#define NN 100000
#define F_IN 128
#define F_OUT 40
#define F_PAD 48        // padded f32 row stride: 192 B
#define BSHIFT 9        // 512 nodes per bucket
#define BSIZE (1 << BSHIFT)
#define NBUCK ((NN + BSIZE - 1) >> BSHIFT)   // 196
#define EPB_A 4096
#define EPB_C 16384

typedef short bf16x8 __attribute__((ext_vector_type(8)));
typedef float f32x4 __attribute__((ext_vector_type(4)));

__device__ __forceinline__ short f2bf(float f) {
    union { float f; unsigned u; } uf; uf.f = f;
    unsigned r = uf.u + 0x7FFF + ((uf.u >> 16) & 1);   // RNE
    return (short)(r >> 16);
}

// ---- phase A: bucket histogram ----
__global__ void bhist_kernel(const int* __restrict__ col, int* __restrict__ bcount, int E) {
    __shared__ int h[NBUCK];
    for (int i = threadIdx.x; i < NBUCK; i += blockDim.x) h[i] = 0;
    __syncthreads();
    int e0 = blockIdx.x * EPB_A;
    int e1 = min(e0 + EPB_A, E);
    for (int e = e0 + threadIdx.x; e < e1; e += blockDim.x)
        atomicAdd(&h[col[e] >> BSHIFT], 1);
    __syncthreads();
    for (int i = threadIdx.x; i < NBUCK; i += blockDim.x)
        if (h[i]) atomicAdd(&bcount[i], h[i]);
}

// ---- phase B: scan bucket counts -> bbase; init bcursor ----
__global__ void bscan_kernel(const int* __restrict__ bcount, int* __restrict__ bbase,
                             int* __restrict__ bcursor) {
    __shared__ int sh[256];
    int i = threadIdx.x;
    int v = (i < NBUCK) ? bcount[i] : 0;
    sh[i] = v;
    __syncthreads();
    for (int off = 1; off < 256; off <<= 1) {
        int t = (i >= off) ? sh[i - off] : 0;
        __syncthreads();
        sh[i] += t;
        __syncthreads();
    }
    if (i < NBUCK) { int b = sh[i] - v; bbase[i] = b; bcursor[i] = b; }
}

// ---- phase C: partition edges into bucket-contiguous staging ----
__global__ void part_kernel(const int* __restrict__ row, const int* __restrict__ col,
                            int* __restrict__ bcursor, int2* __restrict__ staged, int E) {
    __shared__ int h[NBUCK];
    __shared__ int cur[NBUCK];
    for (int i = threadIdx.x; i < NBUCK; i += blockDim.x) h[i] = 0;
    __syncthreads();
    int e0 = blockIdx.x * EPB_C;
    int e1 = min(e0 + EPB_C, E);
    for (int e = e0 + threadIdx.x; e < e1; e += blockDim.x)
        atomicAdd(&h[col[e] >> BSHIFT], 1);
    __syncthreads();
    for (int i = threadIdx.x; i < NBUCK; i += blockDim.x)
        cur[i] = h[i] ? atomicAdd(&bcursor[i], h[i]) : 0;
    __syncthreads();
    for (int e = e0 + threadIdx.x; e < e1; e += blockDim.x) {
        int c = col[e];
        int pos = atomicAdd(&cur[c >> BSHIFT], 1);
        staged[pos] = make_int2(row[e], c);
    }
}

// ---- phase D: per-bucket fine CSR build + deg/offs/ends/dinv ----
__global__ void build_kernel(const int2* __restrict__ staged, const int* __restrict__ bbase,
                             int* __restrict__ adj, int* __restrict__ offs,
                             int* __restrict__ ends, float* __restrict__ dinv, int N, int E) {
    __shared__ int hist[BSIZE];
    __shared__ int cur[BSIZE];
    int bk = blockIdx.x;
    int node0 = bk << BSHIFT;
    int nn = min(BSIZE, N - node0);
    int ebase = bbase[bk];
    int eend = (bk + 1 < NBUCK) ? bbase[bk + 1] : E;
    for (int i = threadIdx.x; i < BSIZE; i += blockDim.x) hist[i] = 0;
    __syncthreads();
    for (int e = ebase + threadIdx.x; e < eend; e += blockDim.x)
        atomicAdd(&hist[staged[e].y - node0], 1);
    __syncthreads();
    int i = threadIdx.x;
    int v = (i < BSIZE) ? hist[i] : 0;
    for (int off = 1; off < BSIZE; off <<= 1) {
        int t = (i < BSIZE && i >= off) ? hist[i - off] : 0;
        __syncthreads();
        if (i < BSIZE) hist[i] += t;
        __syncthreads();
    }
    if (i < BSIZE) {
        int excl = hist[i] - v;
        cur[i] = excl;
        if (i < nn) {
            offs[node0 + i] = ebase + excl;
            ends[node0 + i] = ebase + excl + v;
            dinv[node0 + i] = rsqrtf((float)v + 1.0f);
        }
    }
    __syncthreads();
    for (int e = ebase + threadIdx.x; e < eend; e += blockDim.x) {
        int2 rc = staged[e];
        int pos = atomicAdd(&cur[rc.y - node0], 1);
        adj[ebase + pos] = rc.x;
    }
}

// ---- MFMA gemm: xs1[n][j] = (x[n] . W[:,j]) * dinv[n], bf16 inputs fp32 acc ----
// block = 256 threads = 4 waves, 16 nodes per wave.
// A frag (16x32 per K-step): lane l holds x[node0+(l&15)][32*ks + 8*(l>>4) + i], i=0..7
// B frag (32x16): lane l holds w[32*ks + 8*(l>>4) + i][16*jt + (l&15)]
// D: col = lane&15, row = (lane>>4)*4 + reg
__global__ void __launch_bounds__(256) gemm_kernel(const float* __restrict__ x,
                                                   const float* __restrict__ w,
                                                   const float* __restrict__ dinv,
                                                   float* __restrict__ xs1, int N) {
    __shared__ bf16x8 shB[3][4][64];   // 12 KB packed B fragments
    int t = threadIdx.x;
    for (int idx = t; idx < 3 * 4 * 64; idx += 256) {
        int lane = idx & 63;
        int ks = (idx >> 6) & 3;
        int jt = idx >> 8;
        int j = 16 * jt + (lane & 15);
        int k0 = 32 * ks + 8 * (lane >> 4);
        bf16x8 v;
#pragma unroll
        for (int i = 0; i < 8; ++i)
            v[i] = (j < F_OUT) ? f2bf(w[(k0 + i) * F_OUT + j]) : (short)0;
        shB[jt][ks][lane] = v;
    }
    __syncthreads();
    int wave = t >> 6, lane = t & 63;
    int node0 = blockIdx.x * 64 + wave * 16;
    if (node0 >= N) return;

    const float* xrow = x + (size_t)(node0 + (lane & 15)) * F_IN + 8 * (lane >> 4);
    f32x4 acc0 = {0.f, 0.f, 0.f, 0.f};
    f32x4 acc1 = acc0, acc2 = acc0;
#pragma unroll
    for (int ks = 0; ks < 4; ++ks) {
        float4 lo = *(const float4*)(xrow + 32 * ks);
        float4 hi = *(const float4*)(xrow + 32 * ks + 4);
        bf16x8 a;
        a[0] = f2bf(lo.x); a[1] = f2bf(lo.y); a[2] = f2bf(lo.z); a[3] = f2bf(lo.w);
        a[4] = f2bf(hi.x); a[5] = f2bf(hi.y); a[6] = f2bf(hi.z); a[7] = f2bf(hi.w);
        acc0 = __builtin_amdgcn_mfma_f32_16x16x32_bf16(a, shB[0][ks][lane], acc0, 0, 0, 0);
        acc1 = __builtin_amdgcn_mfma_f32_16x16x32_bf16(a, shB[1][ks][lane], acc1, 0, 0, 0);
        acc2 = __builtin_amdgcn_mfma_f32_16x16x32_bf16(a, shB[2][ks][lane], acc2, 0, 0, 0);
    }
    int colj = lane & 15;
    int rbase = (lane >> 4) * 4;
#pragma unroll
    for (int r = 0; r < 4; ++r) {
        int node = node0 + rbase + r;
        float d = dinv[node];
        float* dst = xs1 + (size_t)node * F_PAD;
        dst[colj]      = acc0[r] * d;
        dst[16 + colj] = acc1[r] * d;
        if (colj < F_OUT - 32) dst[32 + colj] = acc2[r] * d;
    }
}

// ---- hop 1 gather ----
__global__ void hop1_kernel(const int* __restrict__ offs, const int* __restrict__ ends,
                            const int* __restrict__ adj, const float* __restrict__ dinv,
                            const float* __restrict__ xs, float* __restrict__ xs_next, int N) {
    int n = blockIdx.x * 4 + (threadIdx.x >> 6);
    int lane = threadIdx.x & 63;
    if (n >= N || lane >= F_OUT) return;
    int b = offs[n], e = ends[n];
    float a0 = xs[(size_t)n * F_PAD + lane], a1 = 0.f, a2 = 0.f, a3 = 0.f;
    int k = b;
    for (; k + 3 < e; k += 4) {
        int r0 = adj[k], r1 = adj[k + 1], r2 = adj[k + 2], r3 = adj[k + 3];
        a0 += xs[(size_t)r0 * F_PAD + lane];
        a1 += xs[(size_t)r1 * F_PAD + lane];
        a2 += xs[(size_t)r2 * F_PAD + lane];
        a3 += xs[(size_t)r3 * F_PAD + lane];
    }
    for (; k < e; ++k) a0 += xs[(size_t)adj[k] * F_PAD + lane];
    float d = dinv[n];
    xs_next[(size_t)n * F_PAD + lane] = (a0 + a1 + a2 + a3) * d * d;
}

// ---- hop 2 gather + bias + log_softmax ----
__global__ void hop2_kernel(const int* __restrict__ offs, const int* __restrict__ ends,
                            const int* __restrict__ adj, const float* __restrict__ dinv,
                            const float* __restrict__ xs, const float* __restrict__ bias,
                            float* __restrict__ out, int N) {
    int n = blockIdx.x * 4 + (threadIdx.x >> 6);
    int lane = threadIdx.x & 63;
    if (n >= N) return;
    int b = offs[n], e = ends[n];
    if (lane >= F_OUT) e = b;
    float a0 = (lane < F_OUT) ? xs[(size_t)n * F_PAD + lane] : 0.f;
    float a1 = 0.f, a2 = 0.f, a3 = 0.f;
    int k = b;
    for (; k + 3 < e; k += 4) {
        int r0 = adj[k], r1 = adj[k + 1], r2 = adj[k + 2], r3 = adj[k + 3];
        a0 += xs[(size_t)r0 * F_PAD + lane];
        a1 += xs[(size_t)r1 * F_PAD + lane];
        a2 += xs[(size_t)r2 * F_PAD + lane];
        a3 += xs[(size_t)r3 * F_PAD + lane];
    }
    for (; k < e; ++k) a0 += xs[(size_t)adj[k] * F_PAD + lane];

    float logit = 0.f, v = -INFINITY;
    if (lane < F_OUT) {
        logit = (a0 + a1 + a2 + a3) * dinv[n] + bias[lane];
        v = logit;
    }
#pragma unroll
    for (int off = 32; off; off >>= 1) v = fmaxf(v, __shfl_xor(v, off));
    float ex = (lane < F_OUT) ? expf(logit - v) : 0.f;
#pragma unroll
    for (int off = 32; off; off >>= 1) ex += __shfl_xor(ex, off);
    if (lane < F_OUT) out[(size_t)n * F_OUT + lane] = logit - v - logf(ex);
}

extern "C" void kernel_launch(void* const* d_in, const int* in_sizes, int n_in,
                              void* d_out, int out_size, void* d_ws, size_t ws_size,
                              hipStream_t stream) {
    const float* x    = (const float*)d_in[0];
    const int*   eidx = (const int*)d_in[1];
    const float* w    = (const float*)d_in[2];
    const float* bias = (const float*)d_in[3];
    float* out = (float*)d_out;

    const int E = in_sizes[1] / 2;
    const int N = NN;

    char* ws = (char*)d_ws;
    int*   bcount  = (int*)ws;   ws += 256 * 4;
    int*   bbase   = (int*)ws;   ws += 256 * 4;
    int*   bcursor = (int*)ws;   ws += 256 * 4;
    int*   offs    = (int*)ws;   ws += (size_t)N * 4;
    int*   ends    = (int*)ws;   ws += (size_t)N * 4;
    float* dinv    = (float*)ws; ws += (size_t)N * 4;
    int*   adj     = (int*)ws;   ws += (size_t)E * 4;
    float* xs1     = (float*)ws; ws += (size_t)N * F_PAD * 4;
    float* xs2     = (float*)ws;                       // 19.2 MB
    int2*  staged  = (int2*)xs2;                       // aliases xs2 (dead until hop1)

    const int* row = eidx;
    const int* col = eidx + E;

    hipMemsetAsync(bcount, 0, NBUCK * sizeof(int), stream);
    bhist_kernel<<<(E + EPB_A - 1) / EPB_A, 1024, 0, stream>>>(col, bcount, E);
    bscan_kernel<<<1, 256, 0, stream>>>(bcount, bbase, bcursor);
    part_kernel<<<(E + EPB_C - 1) / EPB_C, 1024, 0, stream>>>(row, col, bcursor, staged, E);
    build_kernel<<<NBUCK, 1024, 0, stream>>>(staged, bbase, adj, offs, ends, dinv, N, E);

    gemm_kernel<<<(N + 63) / 64, 256, 0, stream>>>(x, w, dinv, xs1, N);
    hop1_kernel<<<(N + 3) / 4, 256, 0, stream>>>(offs, ends, adj, dinv, xs1, xs2, N);
    hop2_kernel<<<(N + 3) / 4, 256, 0, stream>>>(offs, ends, adj, dinv, xs2, bias, out, N);
}